// Round 4
// baseline (3690.260 us; speedup 1.0000x reference)
//
#include <hip/hip_runtime.h>
#include <cstdint>

#define HID 2048
#define SLEN 2048
#define NH 8
#define HD 256
#define MTOT 4096

constexpr float SCALING = 0.0625f;   // 256^-0.5
constexpr float SOFTCAP = 50.0f;

// ---------------- fp32 GEMM: C[M,N] = A[M,K] @ B[K,N], all row-major ----------------
// 128x128 tile, BK=16, 256 threads, 8x8 accumulators per thread.
__global__ __launch_bounds__(256) void gemm128(
    const float* __restrict__ A, const float* __restrict__ B,
    float* __restrict__ C, int M, int N, int K) {
  __shared__ __align__(16) float As[16][132];  // [k][m], +4 pad
  __shared__ __align__(16) float Bs[16][132];  // [k][n], +4 pad
  const int tid = threadIdx.x;
  const int row0 = blockIdx.y * 128;
  const int col0 = blockIdx.x * 128;
  const int ty = tid >> 4, tx = tid & 15;
  const int a_r = tid >> 2;          // 0..63
  const int a_c = (tid & 3) * 4;     // 0,4,8,12
  const int b_k = tid >> 5;          // 0..7
  const int b_n = (tid & 31) * 4;    // 0..124

  float acc[8][8];
  #pragma unroll
  for (int i = 0; i < 8; ++i)
    #pragma unroll
    for (int j = 0; j < 8; ++j) acc[i][j] = 0.f;

  for (int k0 = 0; k0 < K; k0 += 16) {
    const float4 av0 = *(const float4*)&A[(size_t)(row0 + a_r) * K + k0 + a_c];
    const float4 av1 = *(const float4*)&A[(size_t)(row0 + a_r + 64) * K + k0 + a_c];
    const float4 bv0 = *(const float4*)&B[(size_t)(k0 + b_k) * N + col0 + b_n];
    const float4 bv1 = *(const float4*)&B[(size_t)(k0 + b_k + 8) * N + col0 + b_n];
    __syncthreads();  // previous tile fully consumed before overwrite
    As[a_c + 0][a_r] = av0.x; As[a_c + 1][a_r] = av0.y;
    As[a_c + 2][a_r] = av0.z; As[a_c + 3][a_r] = av0.w;
    As[a_c + 0][a_r + 64] = av1.x; As[a_c + 1][a_r + 64] = av1.y;
    As[a_c + 2][a_r + 64] = av1.z; As[a_c + 3][a_r + 64] = av1.w;
    *(float4*)&Bs[b_k][b_n] = bv0;
    *(float4*)&Bs[b_k + 8][b_n] = bv1;
    __syncthreads();
    #pragma unroll
    for (int kk = 0; kk < 16; ++kk) {
      const float4 A0 = *(const float4*)&As[kk][ty * 8];
      const float4 A1 = *(const float4*)&As[kk][ty * 8 + 4];
      const float4 B0 = *(const float4*)&Bs[kk][tx * 8];
      const float4 B1 = *(const float4*)&Bs[kk][tx * 8 + 4];
      const float a_[8] = {A0.x, A0.y, A0.z, A0.w, A1.x, A1.y, A1.z, A1.w};
      const float b_[8] = {B0.x, B0.y, B0.z, B0.w, B1.x, B1.y, B1.z, B1.w};
      #pragma unroll
      for (int i = 0; i < 8; ++i)
        #pragma unroll
        for (int j = 0; j < 8; ++j)
          acc[i][j] = fmaf(a_[i], b_[j], acc[i][j]);
    }
  }
  #pragma unroll
  for (int i = 0; i < 8; ++i) {
    float* cp = &C[(size_t)(row0 + ty * 8 + i) * N + col0 + tx * 8];
    float4 c0 = {acc[i][0], acc[i][1], acc[i][2], acc[i][3]};
    float4 c1 = {acc[i][4], acc[i][5], acc[i][6], acc[i][7]};
    *(float4*)&cp[0] = c0;
    *(float4*)&cp[4] = c1;
  }
}

// ------------- A-projections + RoPE + rank contraction, one block per token -------------
// Writes q,k,v in [B, NH, S, HD] layout; q pre-scaled by SCALING/Q_RANK, k,v by 1/2.
__global__ __launch_bounds__(256) void qkv_rope(
    const float* __restrict__ hs,
    const float* __restrict__ WAq, const float* __restrict__ WAk,
    const float* __restrict__ WAv,
    const float* __restrict__ Bq, const float* __restrict__ Bk,
    const float* __restrict__ Bv,
    const float* __restrict__ fc, const float* __restrict__ fs,
    float* __restrict__ q, float* __restrict__ k, float* __restrict__ v) {
  const int m = blockIdx.x;        // 0..4095  (b*SLEN + s)
  const int s = m & (SLEN - 1);
  const int b = m >> 11;
  const int tid = threadIdx.x;
  __shared__ __align__(16) float xs[HID];   // hidden row, 8 KB
  __shared__ float part[240];
  __shared__ float Al[80];                  // A_q[48] | A_k[16] | A_v[16]

  #pragma unroll
  for (int it = 0; it < 2; ++it) {
    const int idx = tid + 256 * it;  // float4 index 0..511
    *(float4*)&xs[idx * 4] = *(const float4*)&hs[(size_t)m * HID + idx * 4];
  }
  __syncthreads();

  if (tid < 240) {
    int c = tid % 80;
    const int seg = tid / 80;
    const int kb = (seg * HID) / 3, ke = ((seg + 1) * HID) / 3;
    const float* W; int nc;
    if (c < 48)      { W = WAq; nc = 48; }
    else if (c < 64) { W = WAk; nc = 16; c -= 48; }
    else             { W = WAv; nc = 16; c -= 64; }
    float acc = 0.f;
    for (int kk = kb; kk < ke; ++kk) acc = fmaf(xs[kk], W[(size_t)kk * nc + c], acc);
    part[tid] = acc;
  }
  __syncthreads();
  if (tid < 80) Al[tid] = part[tid] + part[tid + 80] + part[tid + 160];
  __syncthreads();

  const size_t tbase = (size_t)b * NH * SLEN * HD + (size_t)s * HD;
  if (tid < 128) {
    // q: rank 6, 8 heads. Thread owns rope-pair j.
    const int j = tid;
    const float cz = fc[s * 128 + j], sz = fs[s * 128 + j];
    float qe[8], qo[8];
    #pragma unroll
    for (int hh = 0; hh < 8; ++hh) { qe[hh] = 0.f; qo[hh] = 0.f; }
    #pragma unroll
    for (int r = 0; r < 6; ++r) {
      const float2 x = *(const float2*)&Bq[(size_t)m * 1536 + r * 256 + 2 * j];
      const float re = x.x * cz - x.y * sz;
      const float ro = x.x * sz + x.y * cz;
      #pragma unroll
      for (int hh = 0; hh < 8; ++hh) {
        const float a = Al[hh * 6 + r];
        qe[hh] = fmaf(a, re, qe[hh]);
        qo[hh] = fmaf(a, ro, qo[hh]);
      }
    }
    const float qs = SCALING / 6.f;
    #pragma unroll
    for (int hh = 0; hh < 8; ++hh) {
      float2 o; o.x = qe[hh] * qs; o.y = qo[hh] * qs;
      *(float2*)&q[tbase + (size_t)hh * SLEN * HD + 2 * j] = o;
    }
  } else {
    // k (rank 2, roped) and v (rank 2, no rope)
    const int j = tid - 128;
    const float cz = fc[s * 128 + j], sz = fs[s * 128 + j];
    float ke_[8], ko_[8], ve_[8], vo_[8];
    #pragma unroll
    for (int hh = 0; hh < 8; ++hh) { ke_[hh]=0.f; ko_[hh]=0.f; ve_[hh]=0.f; vo_[hh]=0.f; }
    #pragma unroll
    for (int r = 0; r < 2; ++r) {
      const float2 xk = *(const float2*)&Bk[(size_t)m * 512 + r * 256 + 2 * j];
      const float2 xv = *(const float2*)&Bv[(size_t)m * 512 + r * 256 + 2 * j];
      const float re = xk.x * cz - xk.y * sz;
      const float ro = xk.x * sz + xk.y * cz;
      #pragma unroll
      for (int hh = 0; hh < 8; ++hh) {
        const float ak = Al[48 + hh * 2 + r];
        const float av = Al[64 + hh * 2 + r];
        ke_[hh] = fmaf(ak, re, ke_[hh]);
        ko_[hh] = fmaf(ak, ro, ko_[hh]);
        ve_[hh] = fmaf(av, xv.x, ve_[hh]);
        vo_[hh] = fmaf(av, xv.y, vo_[hh]);
      }
    }
    #pragma unroll
    for (int hh = 0; hh < 8; ++hh) {
      float2 ok; ok.x = ke_[hh] * 0.5f; ok.y = ko_[hh] * 0.5f;
      *(float2*)&k[tbase + (size_t)hh * SLEN * HD + 2 * j] = ok;
      float2 ov; ov.x = ve_[hh] * 0.5f; ov.y = vo_[hh] * 0.5f;
      *(float2*)&v[tbase + (size_t)hh * SLEN * HD + 2 * j] = ov;
    }
  }
}

// ------------- causal softcapped attention, fixed-max softmax (scores bounded ±50) -----
// Block: 32 q-rows x 8 lanes. K/V tiles 32x256 in LDS, XOR-swizzled (ch ^= ch>>3)
// so the 8 d-slice readers hit 8 distinct bank groups instead of one.
__global__ __launch_bounds__(256) void attn(
    const float* __restrict__ q, const float* __restrict__ k,
    const float* __restrict__ v, float* __restrict__ out) {
  __shared__ __align__(16) float Ks[32 * 256];  // 32 KB
  __shared__ __align__(16) float Vs[32 * 256];  // 32 KB
  const int tid = threadIdx.x;
  const int i = tid >> 3;     // q row within tile
  const int g = tid & 7;      // d-slice (32 floats)
  const int bh = blockIdx.y;  // b*8 + h
  const int b = bh >> 3;
  const int h = bh & 7;
  const int q0 = blockIdx.x * 32;
  const size_t base = (size_t)bh * SLEN * HD;

  float qr[32];
  {
    const float* qp = &q[base + (size_t)(q0 + i) * HD + g * 32];
    #pragma unroll
    for (int c4 = 0; c4 < 8; ++c4) {
      const float4 t = *(const float4*)&qp[c4 * 4];
      qr[c4*4+0] = t.x; qr[c4*4+1] = t.y; qr[c4*4+2] = t.z; qr[c4*4+3] = t.w;
    }
  }
  float accv[32];
  #pragma unroll
  for (int c = 0; c < 32; ++c) accv[c] = 0.f;
  float den = 0.f;

  const int nkt = (q0 >> 5) + 1;
  const float* kbase = &k[base];
  const float* vbase = &v[base];
  for (int kt = 0; kt < nkt; ++kt) {
    const int k0 = kt * 32;
    __syncthreads();
    #pragma unroll
    for (int it = 0; it < 8; ++it) {
      const int l = tid + 256 * it;  // float4 index within 32x256 tile
      const int row = l >> 6;
      const int ch = l & 63;
      const int chs = ch ^ ((ch >> 3) & 7);
      *(float4*)&Ks[row * 256 + chs * 4] =
          *(const float4*)&kbase[(size_t)(k0 + row) * HD + ch * 4];
      *(float4*)&Vs[row * 256 + chs * 4] =
          *(const float4*)&vbase[(size_t)(k0 + row) * HD + ch * 4];
    }
    __syncthreads();
    const int jmax = min(32, q0 + i - k0 + 1);  // j < jmax are causal-valid
    for (int j = 0; j < 32; ++j) {
      const float* krow = &Ks[j * 256];
      float pd = 0.f;
      #pragma unroll
      for (int c4 = 0; c4 < 8; ++c4) {
        const int chs = (g * 8 + c4) ^ g;
        const float4 t = *(const float4*)&krow[chs * 4];
        pd = fmaf(qr[c4*4+0], t.x, pd);
        pd = fmaf(qr[c4*4+1], t.y, pd);
        pd = fmaf(qr[c4*4+2], t.z, pd);
        pd = fmaf(qr[c4*4+3], t.w, pd);
      }
      pd += __shfl_xor(pd, 1);
      pd += __shfl_xor(pd, 2);
      pd += __shfl_xor(pd, 4);
      const float sc = tanhf(pd * (1.f / SOFTCAP)) * SOFTCAP;
      const float e = (j < jmax) ? __expf(sc - SOFTCAP) : 0.f;
      den += e;
      const float* vrow = &Vs[j * 256];
      #pragma unroll
      for (int c4 = 0; c4 < 8; ++c4) {
        const int chs = (g * 8 + c4) ^ g;
        const float4 t = *(const float4*)&vrow[chs * 4];
        accv[c4*4+0] = fmaf(e, t.x, accv[c4*4+0]);
        accv[c4*4+1] = fmaf(e, t.y, accv[c4*4+1]);
        accv[c4*4+2] = fmaf(e, t.z, accv[c4*4+2]);
        accv[c4*4+3] = fmaf(e, t.w, accv[c4*4+3]);
      }
    }
  }
  const float inv = 1.f / den;
  float* op = &out[((size_t)(b * SLEN + q0 + i)) * (NH * HD) + h * HD + g * 32];
  #pragma unroll
  for (int c4 = 0; c4 < 8; ++c4) {
    float4 o = {accv[c4*4]*inv, accv[c4*4+1]*inv, accv[c4*4+2]*inv, accv[c4*4+3]*inv};
    *(float4*)&op[c4 * 4] = o;
  }
}

extern "C" void kernel_launch(void* const* d_in, const int* in_sizes, int n_in,
                              void* d_out, int out_size, void* d_ws, size_t ws_size,
                              hipStream_t stream) {
  const float* hs  = (const float*)d_in[0];
  const float* fc  = (const float*)d_in[1];
  const float* fs  = (const float*)d_in[2];
  // d_in[3] = mask: pure causal by construction, handled analytically.
  const float* WAq = (const float*)d_in[4];
  const float* WAk = (const float*)d_in[5];
  const float* WAv = (const float*)d_in[6];
  const float* WBq = (const float*)d_in[7];
  const float* WBk = (const float*)d_in[8];
  const float* WBv = (const float*)d_in[9];
  const float* Wo  = (const float*)d_in[10];
  float* out = (float*)d_out;

  // Workspace layout (floats).
  // att ALIASES Bq+Bk: Bq/Bk are last read by qkv_rope, att first written by
  // attn (runs strictly after) -> safe. Peak footprint = 142.6 MB.
  float* ws  = (float*)d_ws;
  float* Bq  = ws;                               // 4096*1536          (25.2 MB)
  float* Bk  = Bq + (size_t)MTOT * 1536;         // 4096*512           ( 8.4 MB)
  float* Bv  = Bk + (size_t)MTOT * 512;          // 4096*512           ( 8.4 MB)
  float* qT  = Bv + (size_t)MTOT * 512;          // [2,8,2048,256]     (33.5 MB)
  float* kT  = qT + (size_t)2 * NH * SLEN * HD;  //                    (33.5 MB)
  float* vT  = kT + (size_t)2 * NH * SLEN * HD;  //                    (33.5 MB)
  float* att = ws;                               // [4096,2048] over Bq+Bk (33.5 MB)

  gemm128<<<dim3(1536 / 128, MTOT / 128), 256, 0, stream>>>(hs, WBq, Bq, MTOT, 1536, HID);
  gemm128<<<dim3(512 / 128,  MTOT / 128), 256, 0, stream>>>(hs, WBk, Bk, MTOT, 512, HID);
  gemm128<<<dim3(512 / 128,  MTOT / 128), 256, 0, stream>>>(hs, WBv, Bv, MTOT, 512, HID);
  qkv_rope<<<MTOT, 256, 0, stream>>>(hs, WAq, WAk, WAv, Bq, Bk, Bv, fc, fs, qT, kT, vT);
  attn<<<dim3(SLEN / 32, 2 * NH), 256, 0, stream>>>(qT, kT, vT, att);
  gemm128<<<dim3(HID / 128, MTOT / 128), 256, 0, stream>>>(att, Wo, out, MTOT, HID, HID);
}

// Round 7
// 2821.929 us; speedup vs baseline: 1.3077x; 1.3077x over previous
//
#include <hip/hip_runtime.h>
#include <cstdint>

#define HID 2048
#define SLEN 2048
#define NH 8
#define HD 256
#define MTOT 4096

constexpr float SCALING = 0.0625f;   // 256^-0.5
constexpr float SOFTCAP = 50.0f;

// ---------------- fp32 GEMM: C[M,N] = A[M,K] @ B[K,N], all row-major ----------------
// 128x128 tile, BK=16, 256 threads, 8x8 accumulators per thread.
__global__ __launch_bounds__(256) void gemm128(
    const float* __restrict__ A, const float* __restrict__ B,
    float* __restrict__ C, int M, int N, int K) {
  __shared__ __align__(16) float As[16][132];  // [k][m], +4 pad
  __shared__ __align__(16) float Bs[16][132];  // [k][n], +4 pad
  const int tid = threadIdx.x;
  const int row0 = blockIdx.y * 128;
  const int col0 = blockIdx.x * 128;
  const int ty = tid >> 4, tx = tid & 15;
  const int a_r = tid >> 2;          // 0..63
  const int a_c = (tid & 3) * 4;     // 0,4,8,12
  const int b_k = tid >> 5;          // 0..7
  const int b_n = (tid & 31) * 4;    // 0..124

  float acc[8][8];
  #pragma unroll
  for (int i = 0; i < 8; ++i)
    #pragma unroll
    for (int j = 0; j < 8; ++j) acc[i][j] = 0.f;

  for (int k0 = 0; k0 < K; k0 += 16) {
    const float4 av0 = *(const float4*)&A[(size_t)(row0 + a_r) * K + k0 + a_c];
    const float4 av1 = *(const float4*)&A[(size_t)(row0 + a_r + 64) * K + k0 + a_c];
    const float4 bv0 = *(const float4*)&B[(size_t)(k0 + b_k) * N + col0 + b_n];
    const float4 bv1 = *(const float4*)&B[(size_t)(k0 + b_k + 8) * N + col0 + b_n];
    __syncthreads();  // previous tile fully consumed before overwrite
    As[a_c + 0][a_r] = av0.x; As[a_c + 1][a_r] = av0.y;
    As[a_c + 2][a_r] = av0.z; As[a_c + 3][a_r] = av0.w;
    As[a_c + 0][a_r + 64] = av1.x; As[a_c + 1][a_r + 64] = av1.y;
    As[a_c + 2][a_r + 64] = av1.z; As[a_c + 3][a_r + 64] = av1.w;
    *(float4*)&Bs[b_k][b_n] = bv0;
    *(float4*)&Bs[b_k + 8][b_n] = bv1;
    __syncthreads();
    #pragma unroll
    for (int kk = 0; kk < 16; ++kk) {
      const float4 A0 = *(const float4*)&As[kk][ty * 8];
      const float4 A1 = *(const float4*)&As[kk][ty * 8 + 4];
      const float4 B0 = *(const float4*)&Bs[kk][tx * 8];
      const float4 B1 = *(const float4*)&Bs[kk][tx * 8 + 4];
      const float a_[8] = {A0.x, A0.y, A0.z, A0.w, A1.x, A1.y, A1.z, A1.w};
      const float b_[8] = {B0.x, B0.y, B0.z, B0.w, B1.x, B1.y, B1.z, B1.w};
      #pragma unroll
      for (int i = 0; i < 8; ++i)
        #pragma unroll
        for (int j = 0; j < 8; ++j)
          acc[i][j] = fmaf(a_[i], b_[j], acc[i][j]);
    }
  }
  #pragma unroll
  for (int i = 0; i < 8; ++i) {
    float* cp = &C[(size_t)(row0 + ty * 8 + i) * N + col0 + tx * 8];
    float4 c0 = {acc[i][0], acc[i][1], acc[i][2], acc[i][3]};
    float4 c1 = {acc[i][4], acc[i][5], acc[i][6], acc[i][7]};
    *(float4*)&cp[0] = c0;
    *(float4*)&cp[4] = c1;
  }
}

// ------------- A-projections + RoPE + rank contraction, one block per token -------------
// Writes q,k,v in [B, NH, S, HD] layout; q pre-scaled by SCALING/Q_RANK, k,v by 1/2.
__global__ __launch_bounds__(256) void qkv_rope(
    const float* __restrict__ hs,
    const float* __restrict__ WAq, const float* __restrict__ WAk,
    const float* __restrict__ WAv,
    const float* __restrict__ Bq, const float* __restrict__ Bk,
    const float* __restrict__ Bv,
    const float* __restrict__ fc, const float* __restrict__ fs,
    float* __restrict__ q, float* __restrict__ k, float* __restrict__ v) {
  const int m = blockIdx.x;        // 0..4095  (b*SLEN + s)
  const int s = m & (SLEN - 1);
  const int b = m >> 11;
  const int tid = threadIdx.x;
  __shared__ __align__(16) float xs[HID];   // hidden row, 8 KB
  __shared__ float part[240];
  __shared__ float Al[80];                  // A_q[48] | A_k[16] | A_v[16]

  #pragma unroll
  for (int it = 0; it < 2; ++it) {
    const int idx = tid + 256 * it;  // float4 index 0..511
    *(float4*)&xs[idx * 4] = *(const float4*)&hs[(size_t)m * HID + idx * 4];
  }
  __syncthreads();

  if (tid < 240) {
    int c = tid % 80;
    const int seg = tid / 80;
    const int kb = (seg * HID) / 3, ke = ((seg + 1) * HID) / 3;
    const float* W; int nc;
    if (c < 48)      { W = WAq; nc = 48; }
    else if (c < 64) { W = WAk; nc = 16; c -= 48; }
    else             { W = WAv; nc = 16; c -= 64; }
    float acc = 0.f;
    for (int kk = kb; kk < ke; ++kk) acc = fmaf(xs[kk], W[(size_t)kk * nc + c], acc);
    part[tid] = acc;
  }
  __syncthreads();
  if (tid < 80) Al[tid] = part[tid] + part[tid + 80] + part[tid + 160];
  __syncthreads();

  const size_t tbase = (size_t)b * NH * SLEN * HD + (size_t)s * HD;
  if (tid < 128) {
    // q: rank 6, 8 heads. Thread owns rope-pair j.
    const int j = tid;
    const float cz = fc[s * 128 + j], sz = fs[s * 128 + j];
    float qe[8], qo[8];
    #pragma unroll
    for (int hh = 0; hh < 8; ++hh) { qe[hh] = 0.f; qo[hh] = 0.f; }
    #pragma unroll
    for (int r = 0; r < 6; ++r) {
      const float2 x = *(const float2*)&Bq[(size_t)m * 1536 + r * 256 + 2 * j];
      const float re = x.x * cz - x.y * sz;
      const float ro = x.x * sz + x.y * cz;
      #pragma unroll
      for (int hh = 0; hh < 8; ++hh) {
        const float a = Al[hh * 6 + r];
        qe[hh] = fmaf(a, re, qe[hh]);
        qo[hh] = fmaf(a, ro, qo[hh]);
      }
    }
    const float qs = SCALING / 6.f;
    #pragma unroll
    for (int hh = 0; hh < 8; ++hh) {
      float2 o; o.x = qe[hh] * qs; o.y = qo[hh] * qs;
      *(float2*)&q[tbase + (size_t)hh * SLEN * HD + 2 * j] = o;
    }
  } else {
    // k (rank 2, roped) and v (rank 2, no rope)
    const int j = tid - 128;
    const float cz = fc[s * 128 + j], sz = fs[s * 128 + j];
    float ke_[8], ko_[8], ve_[8], vo_[8];
    #pragma unroll
    for (int hh = 0; hh < 8; ++hh) { ke_[hh]=0.f; ko_[hh]=0.f; ve_[hh]=0.f; vo_[hh]=0.f; }
    #pragma unroll
    for (int r = 0; r < 2; ++r) {
      const float2 xk = *(const float2*)&Bk[(size_t)m * 512 + r * 256 + 2 * j];
      const float2 xv = *(const float2*)&Bv[(size_t)m * 512 + r * 256 + 2 * j];
      const float re = xk.x * cz - xk.y * sz;
      const float ro = xk.x * sz + xk.y * cz;
      #pragma unroll
      for (int hh = 0; hh < 8; ++hh) {
        const float ak = Al[48 + hh * 2 + r];
        const float av = Al[64 + hh * 2 + r];
        ke_[hh] = fmaf(ak, re, ke_[hh]);
        ko_[hh] = fmaf(ak, ro, ko_[hh]);
        ve_[hh] = fmaf(av, xv.x, ve_[hh]);
        vo_[hh] = fmaf(av, xv.y, vo_[hh]);
      }
    }
    #pragma unroll
    for (int hh = 0; hh < 8; ++hh) {
      float2 ok; ok.x = ke_[hh] * 0.5f; ok.y = ko_[hh] * 0.5f;
      *(float2*)&k[tbase + (size_t)hh * SLEN * HD + 2 * j] = ok;
      float2 ov; ov.x = ve_[hh] * 0.5f; ov.y = vo_[hh] * 0.5f;
      *(float2*)&v[tbase + (size_t)hh * SLEN * HD + 2 * j] = ov;
    }
  }
}

// ------------- causal softcapped attention, fixed-max softmax (scores bounded ±50) -----
// v2b: 512 threads / 64 q-rows per block (2 blocks/CU -> 4 waves/SIMD for latency
// hiding), fused exp2-based tanh+exp (exp2f lowers to v_exp_f32), 4-way split dot
// chains for ILP, heavy-first 1D grid (LPT) against causal imbalance.
// exp(50*tanh(pd/50) - 50) == exp2(-144.26950409 / (exp2(0.0577078016*pd) + 1))
__global__ __launch_bounds__(512, 4) void attn(
    const float* __restrict__ q, const float* __restrict__ k,
    const float* __restrict__ v, float* __restrict__ out) {
  __shared__ __align__(16) float Ks[32 * 256];  // 32 KB
  __shared__ __align__(16) float Vs[32 * 256];  // 32 KB
  const int tid = threadIdx.x;
  const int i = tid >> 3;     // q row within tile, 0..63
  const int g = tid & 7;      // d-slice (32 floats)
  const int bid = blockIdx.x;
  const int qt = 31 - (bid >> 4);   // heavy tiles dispatched first
  const int bh = bid & 15;          // b*8 + h
  const int b = bh >> 3;
  const int h = bh & 7;
  const int q0 = qt * 64;
  const size_t base = (size_t)bh * SLEN * HD;

  float qr[32];
  {
    const float* qp = &q[base + (size_t)(q0 + i) * HD + g * 32];
    #pragma unroll
    for (int c4 = 0; c4 < 8; ++c4) {
      const float4 t = *(const float4*)&qp[c4 * 4];
      qr[c4*4+0] = t.x; qr[c4*4+1] = t.y; qr[c4*4+2] = t.z; qr[c4*4+3] = t.w;
    }
  }
  float accv[32];
  #pragma unroll
  for (int c = 0; c < 32; ++c) accv[c] = 0.f;
  float den = 0.f;

  const int nkt = 2 * qt + 2;
  const float* kb_ = &k[base];
  const float* vb_ = &v[base];
  for (int kt = 0; kt < nkt; ++kt) {
    const int k0 = kt * 32;
    __syncthreads();
    #pragma unroll
    for (int it = 0; it < 4; ++it) {
      const int l = tid + 512 * it;  // float4 index within 32x256 tile
      const int row = l >> 6;
      const int ch = l & 63;
      const int chs = ch ^ ((ch >> 3) & 7);
      *(float4*)&Ks[row * 256 + chs * 4] =
          *(const float4*)&kb_[(size_t)(k0 + row) * HD + ch * 4];
      *(float4*)&Vs[row * 256 + chs * 4] =
          *(const float4*)&vb_[(size_t)(k0 + row) * HD + ch * 4];
    }
    __syncthreads();
    const int jm = min(32, q0 + i - k0 + 1);  // j < jm are causal-valid (may be <=0)
    for (int j = 0; j < 32; ++j) {
      const float* krow = &Ks[j * 256];
      float pdv[4] = {0.f, 0.f, 0.f, 0.f};   // 4 independent chains (depth 8)
      #pragma unroll
      for (int c4 = 0; c4 < 8; ++c4) {
        const float4 t = *(const float4*)&krow[((g * 8 + c4) ^ g) * 4];
        float p = pdv[c4 & 3];
        p = fmaf(qr[c4*4+0], t.x, p);
        p = fmaf(qr[c4*4+1], t.y, p);
        p = fmaf(qr[c4*4+2], t.z, p);
        p = fmaf(qr[c4*4+3], t.w, p);
        pdv[c4 & 3] = p;
      }
      float pd = (pdv[0] + pdv[1]) + (pdv[2] + pdv[3]);
      pd += __shfl_xor(pd, 1);
      pd += __shfl_xor(pd, 2);
      pd += __shfl_xor(pd, 4);
      // fused softcap+exp (fixed-max softmax): e = exp(50*tanh(pd/50) - 50)
      const float t1 = exp2f(pd * 0.0577078016f);
      float e = exp2f(-144.26950409f / (t1 + 1.f));
      if (j >= jm) e = 0.f;
      den += e;
      const float* vrow = &Vs[j * 256];
      #pragma unroll
      for (int c4 = 0; c4 < 8; ++c4) {
        const float4 t = *(const float4*)&vrow[((g * 8 + c4) ^ g) * 4];
        accv[c4*4+0] = fmaf(e, t.x, accv[c4*4+0]);
        accv[c4*4+1] = fmaf(e, t.y, accv[c4*4+1]);
        accv[c4*4+2] = fmaf(e, t.z, accv[c4*4+2]);
        accv[c4*4+3] = fmaf(e, t.w, accv[c4*4+3]);
      }
    }
  }
  const float inv = 1.f / den;
  float* op = &out[((size_t)(b * SLEN + q0 + i)) * (NH * HD) + h * HD + g * 32];
  #pragma unroll
  for (int c4 = 0; c4 < 8; ++c4) {
    float4 o = {accv[c4*4]*inv, accv[c4*4+1]*inv, accv[c4*4+2]*inv, accv[c4*4+3]*inv};
    *(float4*)&op[c4 * 4] = o;
  }
}

extern "C" void kernel_launch(void* const* d_in, const int* in_sizes, int n_in,
                              void* d_out, int out_size, void* d_ws, size_t ws_size,
                              hipStream_t stream) {
  const float* hs  = (const float*)d_in[0];
  const float* fc  = (const float*)d_in[1];
  const float* fs  = (const float*)d_in[2];
  // d_in[3] = mask: pure causal by construction, handled analytically.
  const float* WAq = (const float*)d_in[4];
  const float* WAk = (const float*)d_in[5];
  const float* WAv = (const float*)d_in[6];
  const float* WBq = (const float*)d_in[7];
  const float* WBk = (const float*)d_in[8];
  const float* WBv = (const float*)d_in[9];
  const float* Wo  = (const float*)d_in[10];
  float* out = (float*)d_out;

  // Workspace layout (floats).
  // att ALIASES Bq+Bk: Bq/Bk are last read by qkv_rope, att first written by
  // attn (runs strictly after) -> safe. Peak footprint = 142.6 MB.
  float* ws  = (float*)d_ws;
  float* Bq  = ws;                               // 4096*1536          (25.2 MB)
  float* Bk  = Bq + (size_t)MTOT * 1536;         // 4096*512           ( 8.4 MB)
  float* Bv  = Bk + (size_t)MTOT * 512;          // 4096*512           ( 8.4 MB)
  float* qT  = Bv + (size_t)MTOT * 512;          // [2,8,2048,256]     (33.5 MB)
  float* kT  = qT + (size_t)2 * NH * SLEN * HD;  //                    (33.5 MB)
  float* vT  = kT + (size_t)2 * NH * SLEN * HD;  //                    (33.5 MB)
  float* att = ws;                               // [4096,2048] over Bq+Bk (33.5 MB)

  gemm128<<<dim3(1536 / 128, MTOT / 128), 256, 0, stream>>>(hs, WBq, Bq, MTOT, 1536, HID);
  gemm128<<<dim3(512 / 128,  MTOT / 128), 256, 0, stream>>>(hs, WBk, Bk, MTOT, 512, HID);
  gemm128<<<dim3(512 / 128,  MTOT / 128), 256, 0, stream>>>(hs, WBv, Bv, MTOT, 512, HID);
  qkv_rope<<<MTOT, 256, 0, stream>>>(hs, WAq, WAk, WAv, Bq, Bk, Bv, fc, fs, qT, kT, vT);
  attn<<<dim3(32 * 16), 512, 0, stream>>>(qT, kT, vT, att);
  gemm128<<<dim3(HID / 128, MTOT / 128), 256, 0, stream>>>(att, Wo, out, MTOT, HID, HID);
}